// Round 5
// baseline (384.542 us; speedup 1.0000x reference)
//
#include <hip/hip_runtime.h>
#include <math.h>

// B=16, H=W=28, C=1, KSIZE=5, KNUM=16, VALID stride-1 -> OH=OW=24, P=576.
#define BATCH 16
#define H     28
#define W     28
#define KS    5
#define KN    16
#define OHW   24
#define P     576            // = 9 * 64 exactly
#define PP    (P * P)        // 331776
#define NTHR  256
#define MU_OUT_ELEMS (BATCH * P * KN)
#define G_ELEMS      (BATCH * PP)             // 5,308,416 floats = 20.25 MiB
#define SIG_F4       (BATCH * PP * KN / 4)    // 21,233,664 float4 stores

typedef float vfloat4 __attribute__((ext_vector_type(4)));

// ---------------- Kernel 1: Gram rows + mu_out conv (writes 21.8 MB) --------
__global__ __launch_bounds__(NTHR) void gram_kernel(
    const float* __restrict__ mu_in,    // [16,28,28,1]
    const float* __restrict__ w_mu,     // [5,5,1,16]
    float* __restrict__ G,              // [16,576,576] workspace
    float* __restrict__ out)            // mu_out at offset 0
{
    __shared__ float mu_s[H * W];
    __shared__ float wmu_s[KS * KS * KN];

    const int tid  = threadIdx.x;
    const int wave = tid >> 6;
    const int lane = tid & 63;

    const int blocks_per_b = P / 4;     // 144
    const int b = blockIdx.x / blocks_per_b;
    const int p = (blockIdx.x % blocks_per_b) * 4 + wave;

    const float* mu_b = mu_in + b * (H * W);
    for (int i = tid; i < H * W; i += NTHR) mu_s[i] = mu_b[i];
    for (int i = tid; i < KS * KS * KN; i += NTHR) wmu_s[i] = w_mu[i];
    __syncthreads();

    const int ph = p / OHW;
    const int pw = p % OHW;

    float Xp[KS * KS];
    #pragma unroll
    for (int kh = 0; kh < KS; ++kh)
        #pragma unroll
        for (int kw = 0; kw < KS; ++kw)
            Xp[kh * KS + kw] = mu_s[(ph + kh) * W + (pw + kw)];

    // mu_out row: lanes 0..15, one output channel each.
    if (lane < KN) {
        float acc = 0.f;
        #pragma unroll
        for (int j = 0; j < KS * KS; ++j)
            acc += Xp[j] * wmu_s[j * KN + lane];
        out[(b * P + p) * KN + lane] = acc;
    }

    // Gram row p: g[r] = <Xp, X_{64r+lane}>, stored directly (no shfl needed).
    float* grow = G + (size_t)(b * P + p) * P;
    #pragma unroll
    for (int r = 0; r < 9; ++r) {
        const int q  = r * 64 + lane;
        const int qh = q / OHW;
        const int qw = q % OHW;
        const float* mq = &mu_s[qh * W + qw];
        float acc = 0.f;
        #pragma unroll
        for (int kh = 0; kh < KS; ++kh)
            #pragma unroll
            for (int kw = 0; kw < KS; ++kw)
                acc += Xp[kh * KS + kw] * mq[kh * W + kw];
        grow[q] = acc;   // 256 B coalesced wave-store
    }
}

// ---------------- Kernel 2: fill-clone broadcast (writes 340 MB) ------------
// Sigma[b,p,q,k] = G[b,p,q] * scale[k]; diag (q==k<16) -> abs.
// Pure grid-stride float4 stream: no LDS, no shfl, no barriers — structurally
// identical to the 6.2 TB/s rocclr fill, plus ~15 VALU and a 64B/KB G read.
__global__ __launch_bounds__(NTHR) void bcast_kernel(
    const float* __restrict__ G,
    const float* __restrict__ w_sigma,
    float* __restrict__ out)
{
    const int tid0 = (int)(blockIdx.x * NTHR + threadIdx.x);
    const int S    = (int)(gridDim.x * NTHR);      // stride divisible by 4
    const unsigned c = (unsigned)(tid0 & 3);       // fixed channel group

    const float sc0 = log1pf(expf(w_sigma[4 * c + 0]));
    const float sc1 = log1pf(expf(w_sigma[4 * c + 1]));
    const float sc2 = log1pf(expf(w_sigma[4 * c + 2]));
    const float sc3 = log1pf(expf(w_sigma[4 * c + 3]));

    vfloat4* sig = (vfloat4*)(out + MU_OUT_ELEMS);

    for (int F = tid0; F < SIG_F4; F += S) {
        const unsigned idx = (unsigned)F >> 2;     // G index (b*P+p)*P + q
        const float g = G[idx];
        vfloat4 v = { g * sc0, g * sc1, g * sc2, g * sc3 };
        const unsigned q = idx % (unsigned)P;      // magic-mul division
        if ((q >> 2) == c) {                        // implies q < 16: diag q==k
            const unsigned j = q & 3;
            v[j] = fabsf(v[j]);
        }
        sig[F] = v;
    }
}

// ---------------- Fallback: verified single-kernel (R3) ---------------------
__global__ __launch_bounds__(NTHR) void vdp_fused_kernel(
    const float* __restrict__ mu_in,
    const float* __restrict__ w_mu,
    const float* __restrict__ w_sigma,
    float* __restrict__ out)
{
    __shared__ float mu_s[H * W];
    __shared__ float wmu_s[KS * KS * KN];
    __shared__ float sp_s[KN];

    const int tid  = threadIdx.x;
    const int wave = tid >> 6;
    const int lane = tid & 63;

    const int blocks_per_b = P / 4;
    const int b = blockIdx.x / blocks_per_b;
    const int p = (blockIdx.x % blocks_per_b) * 4 + wave;

    const float* mu_b = mu_in + b * (H * W);
    for (int i = tid; i < H * W; i += NTHR) mu_s[i] = mu_b[i];
    for (int i = tid; i < KS * KS * KN; i += NTHR) wmu_s[i] = w_mu[i];
    if (tid < KN) sp_s[tid] = log1pf(expf(w_sigma[tid]));
    __syncthreads();

    const int ph = p / OHW;
    const int pw = p % OHW;

    float Xp[KS * KS];
    #pragma unroll
    for (int kh = 0; kh < KS; ++kh)
        #pragma unroll
        for (int kw = 0; kw < KS; ++kw)
            Xp[kh * KS + kw] = mu_s[(ph + kh) * W + (pw + kw)];

    if (lane < KN) {
        float acc = 0.f;
        #pragma unroll
        for (int j = 0; j < KS * KS; ++j)
            acc += Xp[j] * wmu_s[j * KN + lane];
        out[(b * P + p) * KN + lane] = acc;
    }

    const int c = lane & 3;
    const float sc0 = sp_s[4 * c + 0];
    const float sc1 = sp_s[4 * c + 1];
    const float sc2 = sp_s[4 * c + 2];
    const float sc3 = sp_s[4 * c + 3];

    vfloat4* rowp = (vfloat4*)(out + MU_OUT_ELEMS + (size_t)(b * P + p) * (P * KN));

    float g[9];
    #pragma unroll
    for (int r = 0; r < 9; ++r) {
        const int q  = r * 64 + lane;
        const int qh = q / OHW;
        const int qw = q % OHW;
        const float* mq = &mu_s[qh * W + qw];
        float acc = 0.f;
        #pragma unroll
        for (int kh = 0; kh < KS; ++kh)
            #pragma unroll
            for (int kw = 0; kw < KS; ++kw)
                acc += Xp[kh * KS + kw] * mq[kh * W + kw];
        g[r] = acc;
    }

    float gq[36];
    #pragma unroll
    for (int s = 0; s < 36; ++s)
        gq[s] = __shfl(g[s >> 2], 16 * (s & 3) + (lane >> 2));

    #pragma unroll
    for (int s = 0; s < 36; ++s) {
        vfloat4 v = { gq[s] * sc0, gq[s] * sc1, gq[s] * sc2, gq[s] * sc3 };
        if (s == 0) {
            const int qq = lane >> 2;
            if ((qq >> 2) == c) {
                const int r2 = qq & 3;
                v[r2] = fabsf(v[r2]);
            }
        }
        rowp[s * 64 + lane] = v;
    }
}

extern "C" void kernel_launch(void* const* d_in, const int* in_sizes, int n_in,
                              void* d_out, int out_size, void* d_ws, size_t ws_size,
                              hipStream_t stream) {
    const float* mu_in   = (const float*)d_in[0];
    const float* w_mu    = (const float*)d_in[1];
    const float* w_sigma = (const float*)d_in[2];
    float* out = (float*)d_out;

    const size_t g_bytes = (size_t)G_ELEMS * sizeof(float);
    if (d_ws != nullptr && ws_size >= g_bytes) {
        float* G = (float*)d_ws;
        gram_kernel<<<dim3(BATCH * P / 4), dim3(NTHR), 0, stream>>>(
            mu_in, w_mu, G, out);
        bcast_kernel<<<dim3(768), dim3(NTHR), 0, stream>>>(
            G, w_sigma, out);
    } else {
        vdp_fused_kernel<<<dim3(BATCH * P / 4), dim3(NTHR), 0, stream>>>(
            mu_in, w_mu, w_sigma, out);
    }
}

// Round 6
// 372.519 us; speedup vs baseline: 1.0323x; 1.0323x over previous
//
#include <hip/hip_runtime.h>
#include <math.h>

// B=16, H=W=28, C=1, KSIZE=5, KNUM=16, VALID stride-1 -> OH=OW=24, P=576.
#define BATCH 16
#define H     28
#define W     28
#define KS    5
#define KN    16
#define OHW   24
#define P     576            // = 9 * 64 exactly
#define PP    (P * P)
#define NTHR  256
#define NROWS (BATCH * P)                 // 9216 Gram rows
#define MU_OUT_ELEMS (BATCH * P * KN)
#define G_ELEMS      (BATCH * PP)         // 20.25 MiB workspace
#define BGRID 512                         // 9216 = 512 * 18 rows/block

typedef float vfloat4 __attribute__((ext_vector_type(4)));

// ---------------- Kernel 1: Gram rows + mu_out conv (unchanged, verified) ---
__global__ __launch_bounds__(NTHR) void gram_kernel(
    const float* __restrict__ mu_in,    // [16,28,28,1]
    const float* __restrict__ w_mu,     // [5,5,1,16]
    float* __restrict__ G,              // [16,576,576] workspace
    float* __restrict__ out)            // mu_out at offset 0
{
    __shared__ float mu_s[H * W];
    __shared__ float wmu_s[KS * KS * KN];

    const int tid  = threadIdx.x;
    const int wave = tid >> 6;
    const int lane = tid & 63;

    const int blocks_per_b = P / 4;     // 144
    const int b = blockIdx.x / blocks_per_b;
    const int p = (blockIdx.x % blocks_per_b) * 4 + wave;

    const float* mu_b = mu_in + b * (H * W);
    for (int i = tid; i < H * W; i += NTHR) mu_s[i] = mu_b[i];
    for (int i = tid; i < KS * KS * KN; i += NTHR) wmu_s[i] = w_mu[i];
    __syncthreads();

    const int ph = p / OHW;
    const int pw = p % OHW;

    float Xp[KS * KS];
    #pragma unroll
    for (int kh = 0; kh < KS; ++kh)
        #pragma unroll
        for (int kw = 0; kw < KS; ++kw)
            Xp[kh * KS + kw] = mu_s[(ph + kh) * W + (pw + kw)];

    if (lane < KN) {
        float acc = 0.f;
        #pragma unroll
        for (int j = 0; j < KS * KS; ++j)
            acc += Xp[j] * wmu_s[j * KN + lane];
        out[(b * P + p) * KN + lane] = acc;
    }

    float* grow = G + (size_t)(b * P + p) * P;
    #pragma unroll
    for (int r = 0; r < 9; ++r) {
        const int q  = r * 64 + lane;
        const int qh = q / OHW;
        const int qw = q % OHW;
        const float* mq = &mu_s[qh * W + qw];
        float acc = 0.f;
        #pragma unroll
        for (int kh = 0; kh < KS; ++kh)
            #pragma unroll
            for (int kw = 0; kw < KS; ++kw)
                acc += Xp[kh * KS + kw] * mq[kh * W + kw];
        grow[q] = acc;
    }
}

// ---------------- Kernel 2: broadcast with NON-DRAINING store stream --------
// Per wave per row: 9 broadcast G loads + 9 x 1KB stores. Loads for the NEXT
// row are issued BEFORE the current row's store burst; vmcnt is in-order, so
// the compiler's wait before using them is a counted wait that leaves the
// store stream in flight. Steady state: stores never drain (fill-like).
// Zero LDS / barriers / shfl; ga/gb statically indexed (no scratch).
__global__ __launch_bounds__(NTHR) void bcast_kernel(
    const float* __restrict__ G,
    const float* __restrict__ w_sigma,
    float* __restrict__ out)
{
    const int tid  = threadIdx.x;
    const int wave = tid >> 6;
    const int lane = tid & 63;
    const int qg   = lane >> 2;   // q offset within 16-wide group
    const int c    = lane & 3;    // channel group (k = 4c..4c+3)

    const float sc0 = log1pf(expf(w_sigma[4 * c + 0]));
    const float sc1 = log1pf(expf(w_sigma[4 * c + 1]));
    const float sc2 = log1pf(expf(w_sigma[4 * c + 2]));
    const float sc3 = log1pf(expf(w_sigma[4 * c + 3]));

    vfloat4* sig4 = (vfloat4*)(out + MU_OUT_ELEMS);
    const bool dlane = ((qg >> 2) == c);   // this lane holds a diag elem at s==0
    const int  dcomp = qg & 3;

    // Row r, wave w: stores s = 9w+j cover q in [16s,16s+16);
    // float4 idx within row = 64s + lane; g = G[r*P + 16s + qg].
#define LOADG(garr, rr)                                                      \
    {                                                                        \
        const float* gp_ = G + (size_t)(rr) * P + wave * 144 + qg;           \
        _Pragma("unroll")                                                    \
        for (int j = 0; j < 9; ++j) garr[j] = gp_[j * 16];                   \
    }

#define BURST(garr, rr)                                                      \
    {                                                                        \
        vfloat4* dst_ = sig4 + (size_t)(rr) * (P * KN / 4) + wave * 576 + lane; \
        _Pragma("unroll")                                                    \
        for (int j = 0; j < 9; ++j) {                                        \
            const float g_ = garr[j];                                        \
            vfloat4 v_ = { g_ * sc0, g_ * sc1, g_ * sc2, g_ * sc3 };         \
            if (wave == 0 && j == 0) {                                       \
                if (dlane) v_[dcomp] = fabsf(v_[dcomp]);                     \
            }                                                                \
            dst_[j * 64] = v_;                                               \
        }                                                                    \
    }

    float ga[9], gb[9];
    const int bx = (int)blockIdx.x;

    LOADG(ga, bx);                       // prologue
    #pragma unroll 1
    for (int i = 0; i < 9; ++i) {        // 18 rows/block, pair-unrolled
        const int ra = bx + 1024 * i;
        LOADG(gb, ra + 512);             // issue next loads BEFORE stores
        BURST(ga, ra);
        if (i != 8) LOADG(ga, ra + 1024);
        BURST(gb, ra + 512);
    }
#undef LOADG
#undef BURST
}

// ---------------- Fallback: verified single-kernel (R3) ---------------------
__global__ __launch_bounds__(NTHR) void vdp_fused_kernel(
    const float* __restrict__ mu_in,
    const float* __restrict__ w_mu,
    const float* __restrict__ w_sigma,
    float* __restrict__ out)
{
    __shared__ float mu_s[H * W];
    __shared__ float wmu_s[KS * KS * KN];
    __shared__ float sp_s[KN];

    const int tid  = threadIdx.x;
    const int wave = tid >> 6;
    const int lane = tid & 63;

    const int blocks_per_b = P / 4;
    const int b = blockIdx.x / blocks_per_b;
    const int p = (blockIdx.x % blocks_per_b) * 4 + wave;

    const float* mu_b = mu_in + b * (H * W);
    for (int i = tid; i < H * W; i += NTHR) mu_s[i] = mu_b[i];
    for (int i = tid; i < KS * KS * KN; i += NTHR) wmu_s[i] = w_mu[i];
    if (tid < KN) sp_s[tid] = log1pf(expf(w_sigma[tid]));
    __syncthreads();

    const int ph = p / OHW;
    const int pw = p % OHW;

    float Xp[KS * KS];
    #pragma unroll
    for (int kh = 0; kh < KS; ++kh)
        #pragma unroll
        for (int kw = 0; kw < KS; ++kw)
            Xp[kh * KS + kw] = mu_s[(ph + kh) * W + (pw + kw)];

    if (lane < KN) {
        float acc = 0.f;
        #pragma unroll
        for (int j = 0; j < KS * KS; ++j)
            acc += Xp[j] * wmu_s[j * KN + lane];
        out[(b * P + p) * KN + lane] = acc;
    }

    const int c = lane & 3;
    const float sc0 = sp_s[4 * c + 0];
    const float sc1 = sp_s[4 * c + 1];
    const float sc2 = sp_s[4 * c + 2];
    const float sc3 = sp_s[4 * c + 3];

    vfloat4* rowp = (vfloat4*)(out + MU_OUT_ELEMS + (size_t)(b * P + p) * (P * KN));

    float g[9];
    #pragma unroll
    for (int r = 0; r < 9; ++r) {
        const int q  = r * 64 + lane;
        const int qh = q / OHW;
        const int qw = q % OHW;
        const float* mq = &mu_s[qh * W + qw];
        float acc = 0.f;
        #pragma unroll
        for (int kh = 0; kh < KS; ++kh)
            #pragma unroll
            for (int kw = 0; kw < KS; ++kw)
                acc += Xp[kh * KS + kw] * mq[kh * W + kw];
        g[r] = acc;
    }

    float gq[36];
    #pragma unroll
    for (int s = 0; s < 36; ++s)
        gq[s] = __shfl(g[s >> 2], 16 * (s & 3) + (lane >> 2));

    #pragma unroll
    for (int s = 0; s < 36; ++s) {
        vfloat4 v = { gq[s] * sc0, gq[s] * sc1, gq[s] * sc2, gq[s] * sc3 };
        if (s == 0) {
            const int qq = lane >> 2;
            if ((qq >> 2) == c) {
                const int r2 = qq & 3;
                v[r2] = fabsf(v[r2]);
            }
        }
        rowp[s * 64 + lane] = v;
    }
}

extern "C" void kernel_launch(void* const* d_in, const int* in_sizes, int n_in,
                              void* d_out, int out_size, void* d_ws, size_t ws_size,
                              hipStream_t stream) {
    const float* mu_in   = (const float*)d_in[0];
    const float* w_mu    = (const float*)d_in[1];
    const float* w_sigma = (const float*)d_in[2];
    float* out = (float*)d_out;

    const size_t g_bytes = (size_t)G_ELEMS * sizeof(float);
    if (d_ws != nullptr && ws_size >= g_bytes) {
        float* G = (float*)d_ws;
        gram_kernel<<<dim3(BATCH * P / 4), dim3(NTHR), 0, stream>>>(
            mu_in, w_mu, G, out);
        bcast_kernel<<<dim3(BGRID), dim3(NTHR), 0, stream>>>(
            G, w_sigma, out);
    } else {
        vdp_fused_kernel<<<dim3(BATCH * P / 4), dim3(NTHR), 0, stream>>>(
            mu_in, w_mu, w_sigma, out);
    }
}

// Round 7
// 343.352 us; speedup vs baseline: 1.1200x; 1.0849x over previous
//
#include <hip/hip_runtime.h>
#include <math.h>

// B=16, H=W=28, C=1, KSIZE=5, KNUM=16, VALID stride-1 -> OH=OW=24, P=576.
#define BATCH 16
#define H     28
#define W     28
#define KS    5
#define KN    16
#define OHW   24
#define P     576           // = 9 * 64 exactly
#define NTHR  256           // 4 waves; one p-row per wave
#define MU_OUT_ELEMS (BATCH * P * KN)

typedef float vfloat4 __attribute__((ext_vector_type(4)));  // native vec for
// __builtin_nontemporal_store (HIP_vector_type float4 is rejected by the builtin)

__global__ __launch_bounds__(NTHR) void vdp_fused_kernel(
    const float* __restrict__ mu_in,    // [16,28,28,1]
    const float* __restrict__ w_mu,     // [5,5,1,16]
    const float* __restrict__ w_sigma,  // [16]
    float* __restrict__ out)
{
    __shared__ float mu_s[H * W];         // 3.1 KB
    __shared__ float wmu_s[KS * KS * KN]; // 1.6 KB
    __shared__ float sp_s[KN];

    const int tid  = threadIdx.x;
    const int wave = tid >> 6;
    const int lane = tid & 63;

    const int blocks_per_b = P / 4;     // 144 (4 p-rows per block, 1 per wave)
    const int b = blockIdx.x / blocks_per_b;
    const int p = (blockIdx.x % blocks_per_b) * 4 + wave;

    // Stage image, conv weights, softplus scales. ONE barrier total.
    const float* mu_b = mu_in + b * (H * W);
    for (int i = tid; i < H * W; i += NTHR) mu_s[i] = mu_b[i];
    for (int i = tid; i < KS * KS * KN; i += NTHR) wmu_s[i] = w_mu[i];
    if (tid < KN) sp_s[tid] = log1pf(expf(w_sigma[tid]));
    __syncthreads();

    const int ph = p / OHW;
    const int pw = p % OHW;

    // Patch p (wave-uniform LDS broadcast reads).
    float Xp[KS * KS];
    #pragma unroll
    for (int kh = 0; kh < KS; ++kh)
        #pragma unroll
        for (int kw = 0; kw < KS; ++kw)
            Xp[kh * KS + kw] = mu_s[(ph + kh) * W + (pw + kw)];

    // mu_out row: lanes 0..15, one output channel each.
    if (lane < KN) {
        float acc = 0.f;
        #pragma unroll
        for (int j = 0; j < KS * KS; ++j)
            acc += Xp[j] * wmu_s[j * KN + lane];
        out[(b * P + p) * KN + lane] = acc;
    }

    // This lane's 4 channels: c = lane&3 -> channels 4c..4c+3.
    const int c = lane & 3;
    const float sc0 = sp_s[4 * c + 0];
    const float sc1 = sp_s[4 * c + 1];
    const float sc2 = sp_s[4 * c + 2];
    const float sc3 = sp_s[4 * c + 3];

    vfloat4* rowp = (vfloat4*)(out + MU_OUT_ELEMS + (size_t)(b * P + p) * (P * KN));

    // Interleaved compute->store: for each r, compute Gram chunk
    // g = <Xp, X_{64r+lane}>, then immediately emit its 4 contiguous
    // 1 KB wave-stores (s = 4r+t). Stores start after 1/9 of the compute,
    // keeping the store pipe fed for the whole kernel. No barriers.
    #pragma unroll
    for (int r = 0; r < 9; ++r) {
        const int q  = r * 64 + lane;
        const int qh = q / OHW;
        const int qw = q % OHW;
        const float* mq = &mu_s[qh * W + qw];
        float g = 0.f;
        #pragma unroll
        for (int kh = 0; kh < KS; ++kh)
            #pragma unroll
            for (int kw = 0; kw < KS; ++kw)
                g += Xp[kh * KS + kw] * mq[kh * W + kw];

        // Store s = 4r+t, lane i -> float4 index f = 64s+i, row pos
        // q' = 16s+(i>>2), held by lane 16*t + (i>>2) of this chunk.
        #pragma unroll
        for (int t = 0; t < 4; ++t) {
            const int s = 4 * r + t;
            const float gq = __shfl(g, 16 * t + (lane >> 2));
            vfloat4 v = { gq * sc0, gq * sc1, gq * sc2, gq * sc3 };
            if (r == 0 && t == 0) {
                // diag: q' = lane>>2 (<16), abs where channel==q' ->
                // c == q'>>2, component q'&3
                const int qq = lane >> 2;
                if ((qq >> 2) == c) {
                    const int r2 = qq & 3;
                    v[r2] = fabsf(v[r2]);
                }
            }
            __builtin_nontemporal_store(v, &rowp[s * 64 + lane]);
        }
    }
}

extern "C" void kernel_launch(void* const* d_in, const int* in_sizes, int n_in,
                              void* d_out, int out_size, void* d_ws, size_t ws_size,
                              hipStream_t stream) {
    const float* mu_in   = (const float*)d_in[0];
    const float* w_mu    = (const float*)d_in[1];
    const float* w_sigma = (const float*)d_in[2];
    float* out = (float*)d_out;

    dim3 grid(BATCH * P / 4);   // 2304 blocks, 1 p-row per wave
    dim3 block(NTHR);
    vdp_fused_kernel<<<grid, block, 0, stream>>>(mu_in, w_mu, w_sigma, out);
}